// Round 7
// baseline (189.546 us; speedup 1.0000x reference)
//
#include <hip/hip_runtime.h>
#include <hip/hip_bf16.h>
#include <stdint.h>

// Problem constants (SpatialDecoder: B=128, N=1024, DM=64, S=2, D_IN=68)
#define NB 128
#define NN 1024
#define NDM 64

typedef __bf16 bf16;
typedef __bf16 bf16x8_t __attribute__((ext_vector_type(8)));
typedef __bf16 bf16x4_t __attribute__((ext_vector_type(4)));
typedef float f32x4 __attribute__((ext_vector_type(4)));

// ---------------------------------------------------------------------------
// k_prep: adj f32->bf16 cast (blocks < 2048) + weight prep (blocks >= 2048).
//  WAT [128][64] bf16 swizzled: WAT[r][cq*8+j] = Wy_h[r][((cq^(r&7))<<3)+j]
//  WYX [128][4] f32 : folded x/m/u rank-4 weights
//  BIAS[128] f32 : W_gc_s @ b_in   (Y bias)
//  W1B [64][64] bf16 : W_out[o][c]      (gc half)
//  A2B [80][64] bf16 : rows 0..63 W_out[o][64+c]; row 64 W_read[64+c]; 65.. 0
//  HBv [64] f32 : b_out[o] + W_out[o,:64].b_gc
// ---------------------------------------------------------------------------
__global__ __launch_bounds__(256) void k_prep(
    const float* __restrict__ adj,
    const float* __restrict__ W_in, const float* __restrict__ b_in,
    const float* __restrict__ W_gc, const float* __restrict__ b_gc,
    const float* __restrict__ W_out, const float* __restrict__ b_out,
    const float* __restrict__ W_read,
    bf16* __restrict__ adjb, bf16* __restrict__ WAT, float* __restrict__ WYX,
    float* __restrict__ BIAS, bf16* __restrict__ W1B, bf16* __restrict__ A2B,
    float* __restrict__ HBv) {
  const int bx = blockIdx.x;
  if (bx < 2048) {
    int i = bx * 256 + threadIdx.x;  // one float4 per thread
    float4 v = reinterpret_cast<const float4*>(adj)[i];
    bf16x4_t r;
    r.x = (bf16)v.x; r.y = (bf16)v.y; r.z = (bf16)v.z; r.w = (bf16)v.w;
    reinterpret_cast<bf16x4_t*>(adjb)[i] = r;
    return;
  }
  int i = (bx - 2048) * 256 + threadIdx.x;
  if (i < 8192) {  // WAT
    int r = i >> 6, cc = i & 63;
    int cq = cc >> 3, j = cc & 7;
    int c = ((cq ^ (r & 7)) << 3) + j;
    int s = r >> 6, o = r & 63;
    float val = 0.f;
    for (int k = 0; k < 64; ++k) val += W_gc[o * 128 + s * 64 + k] * W_in[k * 68 + 4 + c];
    WAT[i] = (bf16)val;
  } else if (i < 8704) {  // WYX
    int idx = i - 8192;
    int r = idx >> 2, jj = idx & 3;
    int s = r >> 6, o = r & 63;
    float val = 0.f;
    for (int k = 0; k < 64; ++k) val += W_gc[o * 128 + s * 64 + k] * W_in[k * 68 + jj];
    WYX[idx] = val;
  } else if (i < 8832) {  // BIAS
    int r = i - 8704;
    int s = r >> 6, o = r & 63;
    float val = 0.f;
    for (int k = 0; k < 64; ++k) val += W_gc[o * 128 + s * 64 + k] * b_in[k];
    BIAS[r] = val;
  } else if (i < 12928) {  // W1B
    int j = i - 8832;
    int o = j >> 6, c = j & 63;
    W1B[j] = (bf16)W_out[o * 128 + c];
  } else if (i < 18048) {  // A2B (80x64)
    int j = i - 12928;
    int r = j >> 6, c = j & 63;
    float val = 0.f;
    if (r < 64) val = W_out[r * 128 + 64 + c];
    else if (r == 64) val = W_read[64 + c];
    A2B[j] = (bf16)val;
  } else if (i < 18112) {  // HBv
    int o = i - 18048;
    float val = b_out[o];
    for (int c = 0; c < 64; ++c) val += W_out[o * 128 + c] * b_gc[c];
    HBv[o] = val;
  }
}

// ---------------------------------------------------------------------------
// k_build (fused transpose + Y build). Grid (8, 128), 256 thr.
//  1) stage h tile [64c x 128v] f32 -> LDS T via global_load_lds
//  2) transpose/pack -> HTs [128v][64c] bf16, XOR-swizzled (cq = kq^(v&7));
//     write same to global HT (for k_gemm phase-3) + h passthrough to out2
//  3) MFMA: Y[b, so, v] = BIAS[so] + WYX[so].x4[v] + sum_c h[c][v]*Wy_h[so][c]
// ---------------------------------------------------------------------------
__global__ __launch_bounds__(256) void k_build(
    const float* __restrict__ x, const float* __restrict__ m, const float* __restrict__ u,
    const float* __restrict__ h, const bf16* __restrict__ WAT,
    const float* __restrict__ WYX, const float* __restrict__ BIAS,
    bf16* __restrict__ Y, bf16* __restrict__ HT, float* __restrict__ out2) {
  __shared__ __align__(16) float T[64 * 128];     // 32 KB
  __shared__ __align__(16) bf16 HTs[128 * 64];    // 16 KB
  __shared__ __align__(16) bf16 WAs[128 * 64];    // 16 KB
  __shared__ __align__(16) float X4L[128 * 4];    // 2 KB
  __shared__ __align__(16) float WYXs[128 * 4];   // 2 KB
  __shared__ __align__(16) float biasL[128];
  const int t = threadIdx.x;
  const int vb = blockIdx.x * 128;
  const int b = blockIdx.y;

  for (int i = t; i < 2048; i += 256)
    __builtin_amdgcn_global_load_lds(
        (const uint32_t*)(h + (size_t)(b * 64 + (i >> 5)) * NN + vb + (i & 31) * 4),
        (uint32_t*)&T[i * 4], 16, 0, 0);
  for (int i = t; i < 1024; i += 256)
    __builtin_amdgcn_global_load_lds((const uint32_t*)(WAT + i * 8), (uint32_t*)&WAs[i * 8], 16, 0, 0);
  if (t < 128)
    __builtin_amdgcn_global_load_lds((const uint32_t*)(WYX + t * 4), (uint32_t*)&WYXs[t * 4], 16, 0, 0);
  if (t < 32)
    __builtin_amdgcn_global_load_lds((const uint32_t*)(BIAS + t * 4), (uint32_t*)&biasL[t * 4], 16, 0, 0);
  if (t < 128) {
    float4 x4;
    x4.x = x[(size_t)b * NN + vb + t];
    x4.y = m[(size_t)b * NN + vb + t];
    x4.z = u[(size_t)(b * 2) * NN + vb + t];
    x4.w = u[(size_t)(b * 2 + 1) * NN + vb + t];
    *reinterpret_cast<float4*>(&X4L[t * 4]) = x4;
  }
  __syncthreads();

  // transpose/pack: thread pair covers one v
  {
    const int v = t >> 1, half = t & 1;
#pragma unroll
    for (int cc = 0; cc < 4; ++cc) {
      int cq = half * 4 + cc;
      int cbase = (cq ^ (v & 7)) << 3;
      bf16x8_t pk;
#pragma unroll
      for (int j = 0; j < 8; ++j) pk[j] = (bf16)T[(cbase + j) * 128 + v];
      *reinterpret_cast<bf16x8_t*>(&HTs[v * 64 + cq * 8]) = pk;
      *reinterpret_cast<bf16x8_t*>(&HT[((size_t)(b << 10) + vb + v) * 64 + cq * 8]) = pk;
    }
  }
  // h passthrough (exact f32)
  for (int i = t; i < 2048; i += 256) {
    int r = i >> 5, ck = i & 31;
    float4 hv = *reinterpret_cast<const float4*>(&T[r * 128 + ck * 4]);
    *reinterpret_cast<float4*>(&out2[(size_t)(b * 128 + 64 + r) * NN + vb + ck * 4]) = hv;
  }
  __syncthreads();

  const int wave = t >> 6, lane = t & 63;
  const int q = lane >> 4, lx = lane & 7, o16 = lane & 15;
  const int offK0 = (q ^ lx) << 3, offK1 = ((q + 4) ^ lx) << 3;

#pragma unroll
  for (int vi = 0; vi < 2; ++vi) {
    const int vt = wave + vi * 4;
    const int vrow = vt * 16 + o16;
    bf16x8_t af0 = *reinterpret_cast<const bf16x8_t*>(&HTs[vrow * 64 + offK0]);
    bf16x8_t af1 = *reinterpret_cast<const bf16x8_t*>(&HTs[vrow * 64 + offK1]);
    float4 x4r[4];
#pragma unroll
    for (int r = 0; r < 4; ++r)
      x4r[r] = *reinterpret_cast<const float4*>(&X4L[(vt * 16 + q * 4 + r) * 4]);
    const int vg = vb + vt * 16 + q * 4;
    for (int nt = 0; nt < 8; ++nt) {
      const int rr = nt * 16 + o16;
      bf16x8_t bf0 = *reinterpret_cast<const bf16x8_t*>(&WAs[rr * 64 + offK0]);
      bf16x8_t bf1 = *reinterpret_cast<const bf16x8_t*>(&WAs[rr * 64 + offK1]);
      float bsv = biasL[rr];
      float4 wy = *reinterpret_cast<const float4*>(&WYXs[rr * 4]);
      f32x4 c0;
#pragma unroll
      for (int r = 0; r < 4; ++r)
        c0[r] = bsv + wy.x * x4r[r].x + wy.y * x4r[r].y + wy.z * x4r[r].z + wy.w * x4r[r].w;
      f32x4 acc = __builtin_amdgcn_mfma_f32_16x16x32_bf16(af0, bf0, c0, 0, 0, 0);
      acc = __builtin_amdgcn_mfma_f32_16x16x32_bf16(af1, bf1, acc, 0, 0, 0);
      const int s = nt >> 2;
      const int o = rr - s * 64;
      bf16x4_t pk;
      pk.x = (bf16)acc[0]; pk.y = (bf16)acc[1]; pk.z = (bf16)acc[2]; pk.w = (bf16)acc[3];
      *reinterpret_cast<bf16x4_t*>(&Y[(size_t)(b * 64 + o) * 2048 + s * 1024 + vg]) = pk;
    }
  }
}

// ---------------------------------------------------------------------------
// k_gemm v3: 64x128 tile (one batch per block), grid (128, 8) = 1024 blocks
// -> 4 blocks/CU. BK=64, XOR swizzle, loop-carried staging pointers.
// Epilogue per block (batch b, cols colB..+128):
//   phase2: out[o,w]  = HB[o] + W1 @ gc        (gc tile in LDS, pad 72)
//   phase3: out[o,w] += [W2;Wr] @ h            (B-frags from swizzled HT,
//                                               A-frags direct from global)
//   PReLU -> out2[b,0..63]; rd-reduce + hread-row -> out0.
// ---------------------------------------------------------------------------
__global__ __launch_bounds__(256, 4) void k_gemm(
    const bf16* __restrict__ Y, const bf16* __restrict__ ADJB,
    const bf16* __restrict__ HT,
    const bf16* __restrict__ W1B, const bf16* __restrict__ A2B,
    const float* __restrict__ HBv, const float* __restrict__ W_read,
    const float* __restrict__ b_read, const float* __restrict__ prelu_w,
    float* __restrict__ out0, float* __restrict__ out2) {
  __shared__ __align__(16) union SMem {
    struct { bf16 As[64 * 64]; bf16 Bs[128 * 64]; } st;   // 8 + 16 KB staging
    bf16 gcs[128 * 72];                                   // 18 KB epilogue gc
  } sm;
  __shared__ float HBs[64];
  __shared__ float Wrs[64];

  const int t = threadIdx.x;
  const int wave = t >> 6, lane = t & 63;
  const int b = blockIdx.x;          // batch; A rows = b*64 .. +64
  const int colB = blockIdx.y * 128;
  const int fr = lane & 15;
  const int q = lane >> 4, lx = lane & 7;
  const int offK0 = (q ^ lx) << 3, offK1 = ((q + 4) ^ lx) << 3;
  const int wn = wave * 32;          // wave's column chunk within the 128

  if (t < 64) { HBs[t] = HBv[t]; Wrs[t] = W_read[t]; }
  const float pw = prelu_w[0];
  const float br = b_read[0];

  f32x4 acc[4][2];
  const f32x4 zero = {0.f, 0.f, 0.f, 0.f};
#pragma unroll
  for (int i = 0; i < 4; ++i)
#pragma unroll
    for (int j = 0; j < 2; ++j) acc[i][j] = zero;

  // loop-carried staging pointers (A: 512 chunks -> 2/thread; B: 1024 -> 4)
  const bf16* aSrc[2]; uint32_t* aDst[2];
#pragma unroll
  for (int j = 0; j < 2; ++j) {
    int c = t + 256 * j;
    int row = c >> 3;
    int qs = (c & 7) ^ (row & 7);
    aSrc[j] = Y + (size_t)(b * 64 + row) * 2048 + qs * 8;
    aDst[j] = (uint32_t*)&sm.st.As[c * 8];
  }
  const bf16* bSrc[4]; uint32_t* bDst[4];
#pragma unroll
  for (int j = 0; j < 4; ++j) {
    int c = t + 256 * j;
    int row = c >> 3;
    int qs = (c & 7) ^ (row & 7);
    bSrc[j] = ADJB + (size_t)(colB + row) * 1024 + qs * 8;
    bDst[j] = (uint32_t*)&sm.st.Bs[c * 8];
  }
  int rAb[4], rBb[2];
#pragma unroll
  for (int i = 0; i < 4; ++i) rAb[i] = (i * 16 + fr) * 64;
#pragma unroll
  for (int j = 0; j < 2; ++j) rBb[j] = (wn + j * 16 + fr) * 64;
  __syncthreads();

  for (int s = 0; s < 2; ++s) {
    for (int kk = 0; kk < 1024; kk += 64) {
#pragma unroll
      for (int j = 0; j < 2; ++j) {
        __builtin_amdgcn_global_load_lds((const uint32_t*)aSrc[j], aDst[j], 16, 0, 0);
        aSrc[j] += 64;
      }
#pragma unroll
      for (int j = 0; j < 4; ++j) {
        __builtin_amdgcn_global_load_lds((const uint32_t*)bSrc[j], bDst[j], 16, 0, 0);
        bSrc[j] += 64;
      }
      __syncthreads();
#pragma unroll
      for (int k2 = 0; k2 < 2; ++k2) {
        const int off = k2 ? offK1 : offK0;
        bf16x8_t af[4], bfr[2];
#pragma unroll
        for (int i = 0; i < 4; ++i)
          af[i] = *reinterpret_cast<const bf16x8_t*>(&sm.st.As[rAb[i] + off]);
#pragma unroll
        for (int j = 0; j < 2; ++j)
          bfr[j] = *reinterpret_cast<const bf16x8_t*>(&sm.st.Bs[rBb[j] + off]);
#pragma unroll
        for (int i = 0; i < 4; ++i)
#pragma unroll
          for (int j = 0; j < 2; ++j)
            acc[i][j] = __builtin_amdgcn_mfma_f32_16x16x32_bf16(af[i], bfr[j], acc[i][j], 0, 0, 0);
      }
      __syncthreads();
    }
    if (s == 0) {
#pragma unroll
      for (int j = 0; j < 4; ++j) bSrc[j] += (1024 * 1024 - 1024);
    }
  }

  // ---- phase 2a: gc tile -> LDS bf16, layout [w(128)][c(64) pad 72] ----
#pragma unroll
  for (int i = 0; i < 4; ++i) {
    const int cc0 = i * 16 + q * 4;
#pragma unroll
    for (int j = 0; j < 2; ++j) {
      const int wl = wn + j * 16 + fr;
      bf16x4_t r;
      r.x = (bf16)acc[i][j][0]; r.y = (bf16)acc[i][j][1];
      r.z = (bf16)acc[i][j][2]; r.w = (bf16)acc[i][j][3];
      *reinterpret_cast<bf16x4_t*>(&sm.gcs[wl * 72 + cc0]) = r;
    }
  }
  __syncthreads();

  f32x4 acc2[5][2];
#pragma unroll
  for (int i = 0; i < 5; ++i)
#pragma unroll
    for (int j = 0; j < 2; ++j) {
      if (i < 4) {
        f32x4 c0;
#pragma unroll
        for (int r = 0; r < 4; ++r) c0[r] = HBs[i * 16 + q * 4 + r];
        acc2[i][j] = c0;
      } else {
        acc2[i][j] = zero;
      }
    }

#pragma unroll
  for (int k2i = 0; k2i < 2; ++k2i) {
    const int k2 = k2i * 32;
    const int off = k2i ? offK1 : offK0;
    // phase 2b: W1 @ gc (A-frags direct from global, B from LDS gc tile)
    bf16x8_t af2[4], bf2[2];
#pragma unroll
    for (int i = 0; i < 4; ++i)
      af2[i] = *reinterpret_cast<const bf16x8_t*>(&W1B[(i * 16 + fr) * 64 + k2 + q * 8]);
#pragma unroll
    for (int j = 0; j < 2; ++j)
      bf2[j] = *reinterpret_cast<const bf16x8_t*>(&sm.gcs[(wn + j * 16 + fr) * 72 + k2 + q * 8]);
#pragma unroll
    for (int i = 0; i < 4; ++i)
#pragma unroll
      for (int j = 0; j < 2; ++j)
        acc2[i][j] = __builtin_amdgcn_mfma_f32_16x16x32_bf16(af2[i], bf2[j], acc2[i][j], 0, 0, 0);
    // phase 3: [W2; Wr] @ h (B-frags direct from swizzled HT global)
    bf16x8_t af3[5], bh[2];
#pragma unroll
    for (int i = 0; i < 5; ++i)
      af3[i] = *reinterpret_cast<const bf16x8_t*>(&A2B[(i * 16 + fr) * 64 + k2 + q * 8]);
#pragma unroll
    for (int j = 0; j < 2; ++j) {
      const int w = colB + wn + j * 16 + fr;
      bh[j] = *reinterpret_cast<const bf16x8_t*>(&HT[((size_t)(b << 10) + w) * 64 + off]);
    }
#pragma unroll
    for (int i = 0; i < 5; ++i)
#pragma unroll
      for (int j = 0; j < 2; ++j)
        acc2[i][j] = __builtin_amdgcn_mfma_f32_16x16x32_bf16(af3[i], bh[j], acc2[i][j], 0, 0, 0);
  }

  // epilogue: PReLU, write out2[b][0..63], reduce read output
  float rd[2] = {0.f, 0.f};
#pragma unroll
  for (int i = 0; i < 4; ++i) {
#pragma unroll
    for (int r = 0; r < 4; ++r) {
      const int o = i * 16 + q * 4 + r;
      const float wr = Wrs[o];
#pragma unroll
      for (int j = 0; j < 2; ++j) {
        const int wg = colB + wn + j * 16 + fr;
        float val = acc2[i][j][r];
        val = val >= 0.f ? val : pw * val;
        out2[(size_t)(b * 128 + o) * 1024 + wg] = val;
        rd[j] += wr * val;
      }
    }
  }
#pragma unroll
  for (int j = 0; j < 2; ++j) {
    rd[j] += __shfl_xor(rd[j], 16, 64);
    rd[j] += __shfl_xor(rd[j], 32, 64);
  }
  if (lane < 16) {
#pragma unroll
    for (int j = 0; j < 2; ++j) {
      const int wg = colB + wn + j * 16 + lane;
      out0[(size_t)b * 1024 + wg] = rd[j] + acc2[4][j][0] + br;
    }
  }
}

// ---------------------------------------------------------------------------
extern "C" void kernel_launch(void* const* d_in, const int* in_sizes, int n_in,
                              void* d_out, int out_size, void* d_ws, size_t ws_size,
                              hipStream_t stream) {
  (void)in_sizes; (void)n_in; (void)out_size; (void)ws_size;
  const float* x       = (const float*)d_in[0];
  const float* m       = (const float*)d_in[1];
  const float* u       = (const float*)d_in[2];
  const float* h       = (const float*)d_in[3];
  const float* adj     = (const float*)d_in[4];
  const float* W_in    = (const float*)d_in[5];
  const float* b_in    = (const float*)d_in[6];
  const float* W_gc    = (const float*)d_in[7];
  const float* b_gc    = (const float*)d_in[8];
  const float* W_out   = (const float*)d_in[9];
  const float* b_out   = (const float*)d_in[10];
  const float* W_read  = (const float*)d_in[11];
  const float* b_read  = (const float*)d_in[12];
  const float* prelu_w = (const float*)d_in[13];

  char* ws = (char*)d_ws;
  bf16*  Y    = (bf16*)(ws);                       // 33554432 B
  bf16*  ADJB = (bf16*)(ws + 33554432);            //  4194304 -> 37748736
  bf16*  HT   = (bf16*)(ws + 37748736);            // 16777216 -> 54525952
  bf16*  WAT  = (bf16*)(ws + 54525952);            //    16384 -> 54542336
  float* WYX  = (float*)(ws + 54542336);           //     2048 -> 54544384
  float* BIAS = (float*)(ws + 54544384);           //      512 -> 54544896
  bf16*  W1B  = (bf16*)(ws + 54544896);            //     8192 -> 54553088
  bf16*  A2B  = (bf16*)(ws + 54553088);            //    10240 -> 54563328
  float* HBv  = (float*)(ws + 54563328);           //      256 -> 54563584

  float* out0 = (float*)d_out;           // read  [B,1,N]  = 131072 f32
  float* out2 = out0 + 131072;           // out2  [B,128,N] f32

  hipLaunchKernelGGL(k_prep,  dim3(2119),     dim3(256), 0, stream,
                     adj, W_in, b_in, W_gc, b_gc, W_out, b_out, W_read,
                     ADJB, WAT, WYX, BIAS, W1B, A2B, HBv);
  hipLaunchKernelGGL(k_build, dim3(8, 128),   dim3(256), 0, stream,
                     x, m, u, h, WAT, WYX, BIAS, Y, HT, out2);
  hipLaunchKernelGGL(k_gemm,  dim3(128, 8),   dim3(256), 0, stream,
                     Y, ADJB, HT, W1B, A2B, HBv, W_read, b_read, prelu_w, out0, out2);
}